// Round 2
// baseline (458.023 us; speedup 1.0000x reference)
//
#include <hip/hip_runtime.h>
#include <stdint.h>
#include <stddef.h>

#define KH   512
#define DF   3072
#define EPSF 1e-5f
#define PPB  8            // positions per block
#define ROWS 48           // PPB * 6

typedef __attribute__((ext_vector_type(4))) float f32x4;
typedef __attribute__((ext_vector_type(8))) short bf16x8;

__device__ __forceinline__ unsigned short f2bf(float f) {
  union { float f; unsigned u; } c; c.f = f;
  unsigned u = c.u;
  u += 0x7fffu + ((u >> 16) & 1u);     // RNE
  return (unsigned short)(u >> 16);
}
__device__ __forceinline__ float bf2f(unsigned short u) {
  union { unsigned u; float f; } c; c.u = ((unsigned)u) << 16;
  return c.f;
}

// Pack Wg = [alpha*gamma | beta_w*gamma] as bf16 rows of 1024 k' per o.
// Also epilogue constants: C1(o) = sum_k (alpha+6*bw)*beta_n + conv_bias,
//                          C2(o) = sum_k (alpha+6*bw)*gamma.
__global__ __launch_bounds__(256) void prep_w(const float* __restrict__ cw,
                                              const float* __restrict__ cb,
                                              const float* __restrict__ nw,
                                              const float* __restrict__ nb,
                                              unsigned short* __restrict__ wbt,
                                              float* __restrict__ c12) {
  const int o = blockIdx.x;
  const int t = threadIdx.x;
  float c1 = 0.f, c2 = 0.f;
  for (int k = t; k < KH; k += 256) {
    float w0 = cw[o * 1024 + 2 * k];
    float w1 = cw[o * 1024 + 2 * k + 1];
    float a  = w0 - w1;
    float g  = nw[k], b = nb[k];
    wbt[(size_t)o * 1024 + k]      = f2bf(a * g);
    wbt[(size_t)o * 1024 + KH + k] = f2bf(w1 * g);
    float tt = a + 6.f * w1;
    c1 += tt * b;
    c2 += tt * g;
  }
  #pragma unroll
  for (int off = 32; off >= 1; off >>= 1) {
    c1 += __shfl_xor(c1, off);
    c2 += __shfl_xor(c2, off);
  }
  __shared__ float s1[4], s2[4];
  int wid = t >> 6, lane = t & 63;
  if (lane == 0) { s1[wid] = c1; s2[wid] = c2; }
  __syncthreads();
  if (t == 0) {
    c12[o]      = s1[0] + s1[1] + s1[2] + s1[3] + cb[o];
    c12[KH + o] = s2[0] + s2[1] + s2[2] + s2[3];
  }
}

// Fused: LN-stats + raw-x LDS panel + barrier-free MFMA K-loop + epilogue.
// Block: 8 positions (48 rows) x 512 o. 8 waves; wave w -> o-slice w*64..+64.
__global__ __launch_bounds__(512, 4) void fused_main(
    const float* __restrict__ x,
    const unsigned short* __restrict__ wbt,
    const float* __restrict__ c12,
    float* __restrict__ out)
{
  __shared__ unsigned short As[ROWS * 512];   // 48 KB raw x bf16, XOR-swizzled rows (1024 B)
  __shared__ unsigned short Sx[PPB * 512];    // 8 KB raw color-sum bf16, swizzled
  __shared__ float st[PPB * 2];               // mean, rstd per local position

  const int tid  = threadIdx.x;
  const int lane = tid & 63;
  const int wid  = tid >> 6;                  // 0..7: position idx AND o-slice idx
  const int r0   = blockIdx.x * PPB;

  // ---- prologue: wave wid owns position r0+wid ----
  {
    const f32x4* x4 = (const f32x4*)(x + (size_t)(r0 + wid) * DF + lane * 48);
    float vv[48];
    #pragma unroll
    for (int i = 0; i < 12; i++) {
      f32x4 q = x4[i];
      vv[4*i] = q.x; vv[4*i+1] = q.y; vv[4*i+2] = q.z; vv[4*i+3] = q.w;
    }
    float s = 0.f, sq = 0.f;
    #pragma unroll
    for (int i = 0; i < 48; i++) { s += vv[i]; sq += vv[i] * vv[i]; }
    #pragma unroll
    for (int off = 32; off >= 1; off >>= 1) {
      s  += __shfl_xor(s,  off);
      sq += __shfl_xor(sq, off);
    }
    float mean = s * (1.f / 3072.f);
    float var  = sq * (1.f / 3072.f) - mean * mean;
    float rstd = rsqrtf(var + EPSF);
    if (lane == 0) { st[2 * wid] = mean; st[2 * wid + 1] = rstd; }
    // raw x -> As (lane holds k = 8*lane..+8, all 6 colors)
    #pragma unroll
    for (int d = 0; d < 6; d++) {
      int row = wid * 6 + d;
      bf16x8 v;
      #pragma unroll
      for (int g = 0; g < 8; g++) v[g] = (short)f2bf(vv[g * 6 + d]);
      *(bf16x8*)((char*)As + row * 1024 + ((lane * 16) ^ ((row & 7) << 4))) = v;
    }
    // raw color-sum -> Sx
    bf16x8 sv;
    #pragma unroll
    for (int g = 0; g < 8; g++) {
      float ss = vv[g*6] + vv[g*6+1] + vv[g*6+2] + vv[g*6+3] + vv[g*6+4] + vv[g*6+5];
      sv[g] = (short)f2bf(ss);
    }
    *(bf16x8*)((char*)Sx + wid * 1024 + ((lane * 16) ^ ((wid & 7) << 4))) = sv;
  }
  __syncthreads();          // the ONLY block-wide barrier

  // ---- barrier-free K loop ----
  f32x4 acc[3][4];
  #pragma unroll
  for (int m = 0; m < 3; m++)
    #pragma unroll
    for (int n = 0; n < 4; n++) acc[m][n] = (f32x4){0.f, 0.f, 0.f, 0.f};

  const int hi16 = (lane >> 4) << 4;
  int aoff[3][2], soff[3][2];
  #pragma unroll
  for (int m = 0; m < 3; m++) {
    int row  = m * 16 + (lane & 15);
    int swz  = (row & 7) << 4;
    int rl   = row / 6;
    int swz2 = (rl & 7) << 4;
    #pragma unroll
    for (int kk = 0; kk < 2; kk++) {
      aoff[m][kk] = row * 1024 + ((kk * 64 + hi16) ^ swz);
      soff[m][kk] = rl * 1024 + ((kk * 64 + hi16) ^ swz2);
    }
  }
  const char* wb = (const char*)wbt;
  int boff[4];
  #pragma unroll
  for (int n = 0; n < 4; n++) {
    int o = wid * 64 + n * 16 + (lane & 15);
    boff[n] = o * 2048 + hi16;
  }

  // k' in [0, 512): A = raw x from As
  #pragma unroll 1
  for (int s = 0; s < 8; s++) {
    bf16x8 bv[4][2], av[3][2];
    #pragma unroll
    for (int n = 0; n < 4; n++)
      #pragma unroll
      for (int kk = 0; kk < 2; kk++)
        bv[n][kk] = *(const bf16x8*)(wb + boff[n] + s * 128 + kk * 64);
    #pragma unroll
    for (int m = 0; m < 3; m++)
      #pragma unroll
      for (int kk = 0; kk < 2; kk++)
        av[m][kk] = *(const bf16x8*)((const char*)As + aoff[m][kk] + s * 128);
    #pragma unroll
    for (int kk = 0; kk < 2; kk++)
      #pragma unroll
      for (int m = 0; m < 3; m++)
        #pragma unroll
        for (int n = 0; n < 4; n++)
          acc[m][n] = __builtin_amdgcn_mfma_f32_16x16x32_bf16(av[m][kk], bv[n][kk], acc[m][n], 0, 0, 0);
  }
  // k' in [512, 1024): A = raw color-sum from Sx
  #pragma unroll 1
  for (int s = 0; s < 8; s++) {
    bf16x8 bv[4][2], av[3][2];
    #pragma unroll
    for (int n = 0; n < 4; n++)
      #pragma unroll
      for (int kk = 0; kk < 2; kk++)
        bv[n][kk] = *(const bf16x8*)(wb + boff[n] + 1024 + s * 128 + kk * 64);
    #pragma unroll
    for (int m = 0; m < 3; m++)
      #pragma unroll
      for (int kk = 0; kk < 2; kk++)
        av[m][kk] = *(const bf16x8*)((const char*)Sx + soff[m][kk] + s * 128);
    #pragma unroll
    for (int kk = 0; kk < 2; kk++)
      #pragma unroll
      for (int m = 0; m < 3; m++)
        #pragma unroll
        for (int n = 0; n < 4; n++)
          acc[m][n] = __builtin_amdgcn_mfma_f32_16x16x32_bf16(av[m][kk], bv[n][kk], acc[m][n], 0, 0, 0);
  }

  // ---- epilogue: h = rstd*acc + C1 - mean*rstd*C2 ; out = x + relu(h) ----
  const int co  = lane & 15;
  const int rvb = (lane >> 4) << 2;
  #pragma unroll
  for (int n = 0; n < 4; n++) {
    const int o = wid * 64 + n * 16 + co;
    const float C1 = c12[o];
    const float C2 = c12[KH + o];
    #pragma unroll
    for (int m = 0; m < 3; m++) {
      #pragma unroll
      for (int v = 0; v < 4; v++) {
        int j  = m * 16 + rvb + v;
        int rl = j / 6;
        int d  = j - rl * 6;
        float mean = st[2 * rl], rstd = st[2 * rl + 1];
        unsigned short rx = *(const unsigned short*)(
            (const char*)As + j * 1024 + ((2 * o) ^ ((j & 7) << 4)));
        float h = rstd * acc[m][n][v] + C1 - mean * rstd * C2;
        h = fmaxf(h, 0.f);
        out[(size_t)(r0 + rl) * DF + o * 6 + d] = bf2f(rx) + h;
      }
    }
  }
}

extern "C" void kernel_launch(void* const* d_in, const int* in_sizes, int n_in,
                              void* d_out, int out_size, void* d_ws, size_t ws_size,
                              hipStream_t stream) {
  (void)n_in; (void)out_size; (void)ws_size;
  const float* x  = (const float*)d_in[0];
  const float* cw = (const float*)d_in[1];
  const float* cb = (const float*)d_in[2];
  const float* nw = (const float*)d_in[3];
  const float* nb = (const float*)d_in[4];
  float* out = (float*)d_out;

  unsigned short* wbt = (unsigned short*)d_ws;                 // 1 MB bf16 weights
  float* c12 = (float*)((char*)d_ws + (size_t)KH * 1024 * 2);  // 4 KB constants

  prep_w<<<512, 256, 0, stream>>>(cw, cb, nw, nb, wbt, c12);

  const int R = in_sizes[0] / DF;          // 24576 positions
  fused_main<<<R / PPB, 512, 0, stream>>>(x, wbt, c12, out);
}

// Round 3
// 422.849 us; speedup vs baseline: 1.0832x; 1.0832x over previous
//
#include <hip/hip_runtime.h>
#include <stdint.h>
#include <stddef.h>

#define KH    512
#define DF    3072
#define EPSF  1e-5f
#define PPB   16
#define ROWS  96            // PPB*6
#define NSTEP 32            // K'=1024 / BK=32
#define BSTEP 32768         // bytes per pre-swizzled B step-block

typedef __attribute__((ext_vector_type(4))) float f32x4;
typedef __attribute__((ext_vector_type(8))) short bf16x8;

__device__ __forceinline__ unsigned short f2bf(float f) {
  union { float f; unsigned u; } c; c.f = f;
  unsigned u = c.u;
  u += 0x7fffu + ((u >> 16) & 1u);     // RNE
  return (unsigned short)(u >> 16);
}
__device__ __forceinline__ float bf2f(unsigned short u) {
  union { unsigned u; float f; } c; c.u = ((unsigned)u) << 16;
  return c.f;
}

__device__ __forceinline__ void gload_lds16(const void* g, void* l) {
  __builtin_amdgcn_global_load_lds(
      (const __attribute__((address_space(1))) void*)g,
      (__attribute__((address_space(3))) void*)l, 16, 0, 0);
}

// Pre-swizzled weight image: 32 step-blocks of 32 KB. Within step s
// (k' in [32s,32s+32)), weight for (o, kin) lands at byte
//   o*64 + ((h ^ (o&3))<<4) + e*2,   h = kin>>3, e = kin&7
// so a linear global_load_lds DMA reproduces exactly the LDS image the
// conflict-free ds_read_b128 B-fragment reads expect.
// Values: k'<512 -> alpha*gamma ; k'>=512 -> beta_w*gamma.
// Also epilogue constants C1(o), C2(o).
__global__ __launch_bounds__(256) void prep_w(const float* __restrict__ cw,
                                              const float* __restrict__ cb,
                                              const float* __restrict__ nw,
                                              const float* __restrict__ nb,
                                              unsigned char* __restrict__ wbt,
                                              float* __restrict__ c12) {
  const int o = blockIdx.x;
  const int t = threadIdx.x;
  float c1 = 0.f, c2 = 0.f;
  for (int k = t; k < KH; k += 256) {
    float w0 = cw[o * 1024 + 2 * k];
    float w1 = cw[o * 1024 + 2 * k + 1];
    float a  = w0 - w1;
    float g  = nw[k], b = nb[k];
    unsigned short va = f2bf(a * g);
    unsigned short vb = f2bf(w1 * g);
    {
      int kp = k;                              // alpha half
      int s = kp >> 5, kin = kp & 31, h = kin >> 3, e = kin & 7;
      *(unsigned short*)(wbt + (size_t)s * BSTEP + o * 64 +
                         ((h ^ (o & 3)) << 4) + e * 2) = va;
    }
    {
      int kp = k + KH;                         // beta half
      int s = kp >> 5, kin = kp & 31, h = kin >> 3, e = kin & 7;
      *(unsigned short*)(wbt + (size_t)s * BSTEP + o * 64 +
                         ((h ^ (o & 3)) << 4) + e * 2) = vb;
    }
    float tt = a + 6.f * w1;
    c1 += tt * b;
    c2 += tt * g;
  }
  #pragma unroll
  for (int off = 32; off >= 1; off >>= 1) {
    c1 += __shfl_xor(c1, off);
    c2 += __shfl_xor(c2, off);
  }
  __shared__ float s1[4], s2[4];
  int wid = t >> 6, lane = t & 63;
  if (lane == 0) { s1[wid] = c1; s2[wid] = c2; }
  __syncthreads();
  if (t == 0) {
    c12[o]      = s1[0] + s1[1] + s1[2] + s1[3] + cb[o];
    c12[KH + o] = s2[0] + s2[1] + s2[2] + s2[3];
  }
}

// Block: 16 positions (96 rows) x 512 o. 1024 threads = 16 waves (2x8).
// B staged per-step (32 KB) into LDS via global_load_lds DMA, shared by all
// waves. A panel (raw x, bf16) built once from contiguous cooperative loads.
__global__ __launch_bounds__(1024, 4) void fused_main(
    const float* __restrict__ x,
    const unsigned char* __restrict__ wbt,
    const float* __restrict__ c12,
    float* __restrict__ out)
{
  __shared__ unsigned char As[ROWS * 1024];   // 96 KB bf16 panel, granule-swizzled
  __shared__ unsigned char Sx[PPB * 1024];    // 16 KB color-sum panel
  __shared__ unsigned char Bs[BSTEP];         // 32 KB B step-tile
  __shared__ float st[PPB * 2];

  const int tid  = threadIdx.x;
  const int lane = tid & 63;
  const int wid  = tid >> 6;                  // 0..15
  const int wm   = wid >> 3;                  // 0..1
  const int wn   = wid & 7;                   // 0..7
  const int co   = lane & 15;
  const int h    = lane >> 4;                 // 0..3
  const int r0   = blockIdx.x * PPB;

  // ---- P1: cooperative contiguous load (4 lines/inst) ----
  const float* xb = x + (size_t)r0 * DF;
  f32x4 q[12];
  #pragma unroll
  for (int i = 0; i < 12; i++) q[i] = *(const f32x4*)(xb + i * 4096 + tid * 4);

  // ---- P2a: scatter bf16 into As (row = pl*6+d, k-major, XOR-swizzled) ----
  #pragma unroll
  for (int i = 0; i < 12; i++) {
    int base = i * 4096 + tid * 4;
    int pl   = base / 3072;
    int rem  = base - pl * 3072;
    int k0   = rem / 6;
    int d0   = rem - k0 * 6;
    #pragma unroll
    for (int e = 0; e < 4; e++) {
      int d = d0 + e, k = k0;
      if (d >= 6) { d -= 6; k += 1; }
      int row  = pl * 6 + d;
      int byte = row * 1024 + ((((k >> 3) ^ (row & 7)) << 4)) + (k & 7) * 2;
      *(unsigned short*)(As + byte) = f2bf(q[i][e]);
    }
  }
  __syncthreads();

  // ---- P2b: wave wid owns position wid: stats + color-sum panel ----
  {
    float vals[48];
    #pragma unroll
    for (int d = 0; d < 6; d++) {
      int row = wid * 6 + d;
      bf16x8 v = *(const bf16x8*)(As + row * 1024 + (((lane ^ (row & 7)) << 4)));
      #pragma unroll
      for (int g = 0; g < 8; g++) vals[d * 8 + g] = bf2f((unsigned short)v[g]);
    }
    float s = 0.f, sq = 0.f;
    #pragma unroll
    for (int i = 0; i < 48; i++) { s += vals[i]; sq += vals[i] * vals[i]; }
    #pragma unroll
    for (int off = 32; off >= 1; off >>= 1) {
      s  += __shfl_xor(s,  off);
      sq += __shfl_xor(sq, off);
    }
    float mean = s * (1.f / 3072.f);
    float var  = sq * (1.f / 3072.f) - mean * mean;
    float rstd = rsqrtf(var + EPSF);
    if (lane == 0) { st[2 * wid] = mean; st[2 * wid + 1] = rstd; }
    bf16x8 sv;
    #pragma unroll
    for (int g = 0; g < 8; g++) {
      float ss = vals[g] + vals[8 + g] + vals[16 + g] + vals[24 + g] +
                 vals[32 + g] + vals[40 + g];
      sv[g] = (short)f2bf(ss);
    }
    *(bf16x8*)(Sx + wid * 1024 + (((lane ^ (wid & 7)) << 4))) = sv;
  }

  // ---- K-loop setup ----
  f32x4 acc[3][4];
  #pragma unroll
  for (int m = 0; m < 3; m++)
    #pragma unroll
    for (int n = 0; n < 4; n++) acc[m][n] = (f32x4){0.f, 0.f, 0.f, 0.f};

  int arow[3], ar7[3], srow[3], sr7[3], boff[4];
  #pragma unroll
  for (int m = 0; m < 3; m++) {
    int row = wm * 48 + m * 16 + co;
    arow[m] = row * 1024;  ar7[m] = row & 7;
    int rl  = row / 6;
    srow[m] = rl * 1024;   sr7[m] = rl & 7;
  }
  #pragma unroll
  for (int n = 0; n < 4; n++) {
    int o = wn * 64 + n * 16 + co;
    boff[n] = o * 64 + ((h ^ (o & 3)) << 4);
  }

  // ---- single-buffered K loop: 32 steps of BK=32 ----
  #pragma unroll 1
  for (int s = 0; s < NSTEP; s++) {
    __syncthreads();                               // Bs free
    {
      const unsigned char* g = wbt + (size_t)s * BSTEP;
      int c0 = wid * 1024;
      int c1 = (16 + wid) * 1024;
      gload_lds16(g + c0 + lane * 16, Bs + c0);
      gload_lds16(g + c1 + lane * 16, Bs + c1);
    }
    __syncthreads();                               // DMA drained (vmcnt 0)

    bf16x8 bv[4], af[3];
    #pragma unroll
    for (int n = 0; n < 4; n++) bv[n] = *(const bf16x8*)(Bs + boff[n]);
    if (s < 16) {
      int g6 = s * 4 + h;
      #pragma unroll
      for (int m = 0; m < 3; m++)
        af[m] = *(const bf16x8*)(As + arow[m] + ((g6 ^ ar7[m]) << 4));
    } else {
      int g6 = (s - 16) * 4 + h;
      #pragma unroll
      for (int m = 0; m < 3; m++)
        af[m] = *(const bf16x8*)(Sx + srow[m] + ((g6 ^ sr7[m]) << 4));
    }
    #pragma unroll
    for (int m = 0; m < 3; m++)
      #pragma unroll
      for (int n = 0; n < 4; n++)
        acc[m][n] = __builtin_amdgcn_mfma_f32_16x16x32_bf16(af[m], bv[n], acc[m][n], 0, 0, 0);
  }

  // ---- epilogue: h = rstd*acc + C1 - mean*rstd*C2 ; out = x + relu(h) ----
  const int rvb = (lane >> 4) << 2;
  #pragma unroll
  for (int n = 0; n < 4; n++) {
    const int o  = wn * 64 + n * 16 + co;
    const float C1 = c12[o];
    const float C2 = c12[KH + o];
    #pragma unroll
    for (int m = 0; m < 3; m++) {
      #pragma unroll
      for (int v = 0; v < 4; v++) {
        int j  = wm * 48 + m * 16 + rvb + v;
        int pl = j / 6;
        int d  = j - pl * 6;
        float mean = st[2 * pl], rstd = st[2 * pl + 1];
        unsigned short rx = *(const unsigned short*)(
            As + j * 1024 + ((((o >> 3) ^ (j & 7)) << 4)) + (o & 7) * 2);
        float hh = rstd * acc[m][n][v] + C1 - mean * rstd * C2;
        hh = fmaxf(hh, 0.f);
        out[(size_t)(r0 + pl) * DF + o * 6 + d] = bf2f(rx) + hh;
      }
    }
  }
}

extern "C" void kernel_launch(void* const* d_in, const int* in_sizes, int n_in,
                              void* d_out, int out_size, void* d_ws, size_t ws_size,
                              hipStream_t stream) {
  (void)n_in; (void)out_size; (void)ws_size;
  const float* x  = (const float*)d_in[0];
  const float* cw = (const float*)d_in[1];
  const float* cb = (const float*)d_in[2];
  const float* nw = (const float*)d_in[3];
  const float* nb = (const float*)d_in[4];
  float* out = (float*)d_out;

  unsigned char* wbt = (unsigned char*)d_ws;                    // 1 MB image
  float* c12 = (float*)((char*)d_ws + (size_t)NSTEP * BSTEP);   // 4 KB

  prep_w<<<512, 256, 0, stream>>>(cw, cb, nw, nb, wbt, c12);

  const int R = in_sizes[0] / DF;            // 24576 positions
  fused_main<<<R / PPB, 1024, 0, stream>>>(x, wbt, c12, out);
}